// Round 15
// baseline (55.005 us; speedup 1.0000x reference)
//
#include <hip/hip_runtime.h>

typedef float v2f __attribute__((ext_vector_type(2)));

constexpr int NX = 192, NY = 192, NZ = 192, NB = 2;
constexpr int ZPT  = 4;            // z outputs per thread
constexpr int TZ   = NZ / ZPT;     // 48
constexpr int BY   = 4;            // y rows per block
constexpr int XSEG = 8;            // x outputs per block (rolled loop)
constexpr int BLOCK_THREADS = TZ * BY;   // 192 = 3 waves
constexpr int PLANE = NY * NZ;
constexpr int NXB = NX / XSEG;     // 24
constexpr int NYB = NY / BY;       // 48
constexpr int NBLK = NYB * NXB * NB;     // 2304 blocks
constexpr int RSTR = 196;                // 4-float zeroed pad prefix + 192 data
constexpr int NROWS = 12;                // 2 tensors x 6 rows
constexpr int TILE_F = NROWS * RSTR + 4; // + trailing pad for last row's z+4 read
constexpr int PADS   = (NROWS + 1) * 4;  // 52 pad floats per buffer

// Fold one staged x-plane from LDS. Row data starts at +4; pads are zero, so
// edge taps at z0-1 / z0+4 are always in-bounds and give exact 0 at volume
// boundaries (matches MONAI zero padding).
template<bool SAFE>
__device__ __forceinline__ void foldLDS(const float* __restrict__ buf,
    int ty, int z0, const float wy[3], float wx, v2f W[5][2])
{
    v2f S[5][3];
    #pragma unroll
    for (int r = 0; r < 3; ++r) {
        const float* Lt = buf + 4 + (ty + r) * RSTR;    // label row data
        const float* Lp = Lt + 6 * RSTR;                // pred row data
        const float4 t4 = *reinterpret_cast<const float4*>(Lt + z0);
        const float4 p4 = *reinterpret_cast<const float4*>(Lp + z0);
        const float tm = Lt[z0 - 1], te = Lt[z0 + 4];
        const float pm = Lp[z0 - 1], pe = Lp[z0 + 4];
        v2f T[3]  = { v2f{tm, t4.x}, v2f{t4.y, t4.z}, v2f{t4.w, te} };
        v2f Pv[3] = { v2f{pm, p4.x}, v2f{p4.y, p4.z}, v2f{p4.w, pe} };
        if (!SAFE) {
            const float wr = wx * wy[r];                // w in {0,1} => exact
            #pragma unroll
            for (int q = 0; q < 3; ++q) { T[q] *= wr; Pv[q] *= wr; }
        }
        #pragma unroll
        for (int q = 0; q < 3; ++q) {
            if (r == 0) {
                S[0][q] = T[q];  S[1][q] = Pv[q];
                S[2][q] = T[q] * T[q];  S[3][q] = Pv[q] * Pv[q];  S[4][q] = T[q] * Pv[q];
            } else {
                S[0][q] += T[q];  S[1][q] += Pv[q];
                S[2][q] += T[q] * T[q];  S[3][q] += Pv[q] * Pv[q];  S[4][q] += T[q] * Pv[q];
            }
        }
    }
    #pragma unroll
    for (int q = 0; q < 5; ++q) {
        const float s0 = S[q][0].x, s1 = S[q][0].y, s2 = S[q][1].x;
        const float s3 = S[q][1].y, s4 = S[q][2].x, s5 = S[q][2].y;
        const float m12 = s1 + s2, m34 = s3 + s4;
        W[q][0] = v2f{s0 + m12, m12 + s3};
        W[q][1] = v2f{s2 + m34, m34 + s5};
    }
}

__device__ __forceinline__ float epilogue4(const v2f P[5][2], const v2f Wn[5][2])
{
    constexpr float inv_vol = 1.0f / 27.0f;
    float acc = 0.f;
    #pragma unroll
    for (int h = 0; h < 2; ++h) {
        const v2f st  = P[0][h] + Wn[0][h];
        const v2f sp  = P[1][h] + Wn[1][h];
        const v2f st2 = P[2][h] + Wn[2][h];
        const v2f sp2 = P[3][h] + Wn[3][h];
        const v2f stp = P[4][h] + Wn[4][h];
        const v2f tavg = st * inv_vol;
        const v2f pavg = sp * inv_vol;
        const v2f cross = stp - pavg * st;
        const v2f tvp   = st2 - tavg * st;
        const v2f pvp   = sp2 - pavg * sp;
        const v2f cc    = cross * cross;
        #pragma unroll
        for (int c = 0; c < 2; ++c) {
            const float tvar = fmaxf(tvp[c], 0.f);
            const float pvar = fmaxf(pvp[c], 0.f);
            acc += cc[c] * __builtin_amdgcn_rcpf(fmaf(tvar, pvar, 1e-5f));
        }
    }
    return acc;
}

// March over XSEG+2 = 10 x-planes: prologue (3) + rolled 2-step loop (3 iters)
// + epilogue. Buffer schedule: plane0->b0, plane1->b1, plane2->b0; then
// fold(b0, 2+2k) / write b1<-3+2k ; fold(b1, 3+2k) / write b0<-4+2k.
template<bool SAFE>
__device__ __forceinline__ float march(
    const float* sb0, const float* sb1, const float* sb2,
    int lo0, int lo1, int lo2, int padoff,
    float (*tile)[TILE_F],
    int ty, int z0, const float wy[3], int xs0)
{
    v2f U[5][2], V[5][2], P[5][2];
    float acc = 0.f;
    float4 G0, G1, G2;

#define XOFF(K) (SAFE ? (xs0 - 1 + (K)) * PLANE \
                      : min(max(xs0 - 1 + (K), 0), NX - 1) * PLANE)
#define WXK(K)  (SAFE ? 1.f : (((unsigned)(xs0 - 1 + (K)) < (unsigned)NX) ? 1.f : 0.f))
#define GLOAD(K) do { const int _xo = XOFF(K);                                  \
        G0 = *reinterpret_cast<const float4*>(sb0 + _xo);                       \
        G1 = *reinterpret_cast<const float4*>(sb1 + _xo);                       \
        G2 = *reinterpret_cast<const float4*>(sb2 + _xo); } while (0)
#define DSWR(B) do { float* _d = tile[(B)];                                     \
        *reinterpret_cast<float4*>(_d + lo0) = G0;                              \
        *reinterpret_cast<float4*>(_d + lo1) = G1;                              \
        *reinterpret_cast<float4*>(_d + lo2) = G2; } while (0)
#define FOLD(B, K, WDST) foldLDS<SAFE>(tile[(B)], ty, z0, wy, WXK(K), WDST)
#define PSET(A, B) do { _Pragma("unroll")                                       \
        for (int q = 0; q < 5; ++q) { _Pragma("unroll")                         \
            for (int h = 0; h < 2; ++h) P[q][h] = A[q][h] + B[q][h]; } } while (0)

    // prologue; zero the pad slots once (both buffers) before first fold
    GLOAD(0); DSWR(0);
    if (padoff >= 0) { tile[0][padoff] = 0.f; tile[1][padoff] = 0.f; }
    __syncthreads();
    GLOAD(1); FOLD(0, 0, U);                DSWR(1); __syncthreads();
    GLOAD(2); FOLD(1, 1, V); PSET(U, V);    DSWR(0); __syncthreads();

    #pragma unroll 1
    for (int k = 0; k < XSEG / 2 - 1; ++k) {
        GLOAD(3 + 2 * k); FOLD(0, 2 + 2 * k, U);
        acc += epilogue4(P, U); PSET(V, U); DSWR(1); __syncthreads();
        GLOAD(4 + 2 * k); FOLD(1, 3 + 2 * k, V);
        acc += epilogue4(P, V); PSET(U, V); DSWR(0); __syncthreads();
    }

    GLOAD(9); FOLD(0, 8, U); acc += epilogue4(P, U); PSET(V, U); DSWR(1); __syncthreads();
              FOLD(1, 9, V); acc += epilogue4(P, V);

#undef XOFF
#undef WXK
#undef GLOAD
#undef DSWR
#undef FOLD
#undef PSET
    return acc;
}

__global__ __launch_bounds__(BLOCK_THREADS, 3)
void ncc_partial(const float* __restrict__ pred, const float* __restrict__ label,
                 float* __restrict__ partials)
{
    __shared__ alignas(16) float tile[2][TILE_F];    // 18,848 B

    const int tx  = threadIdx.x;
    const int ty  = threadIdx.y;
    const int tid = tx + ty * TZ;
    const int z0  = tx * ZPT;
    const int y0  = blockIdx.x * BY;
    const int y   = y0 + ty;
    const int xs0 = blockIdx.y * XSEG;
    const int b   = blockIdx.z;
    const int bbase = b * NX * PLANE;

    // staging: flat float4-index j = r*192 + tid over [tensor(2)][row(6)][z4(48)]
    const float* sb[3];
    int lo[3];
    #pragma unroll
    for (int r = 0; r < 3; ++r) {
        const int j   = r * BLOCK_THREADS + tid;
        const int tt  = j / 288, rem = j - tt * 288;
        const int row = rem / 48, z4 = rem - row * 48;
        int grow = y0 - 1 + row;
        grow = min(max(grow, 0), NY - 1);
        sb[r] = (tt ? pred : label) + bbase + grow * NZ + z4 * 4;
        lo[r] = (tt * 6 + row) * RSTR + 4 + z4 * 4;
    }
    // pad-zeroing assignment: tid < 52 covers all (NROWS+1)*4 pad floats
    const int padoff = (tid < PADS) ? (tid / 4) * RSTR + (tid & 3) : -1;

    float wy[3];
    #pragma unroll
    for (int r = 0; r < 3; ++r) {
        const int yy = y + r - 1;
        wy[r] = ((unsigned)yy < (unsigned)NY) ? 1.f : 0.f;
    }

    const bool safe = (blockIdx.x >= 1) && (blockIdx.x <= NYB - 2) &&
                      (blockIdx.y >= 1) && (blockIdx.y <= NXB - 2);

    const float acc = safe
        ? march<true >(sb[0], sb[1], sb[2], lo[0], lo[1], lo[2], padoff, tile,
                       ty, z0, wy, xs0)
        : march<false>(sb[0], sb[1], sb[2], lo[0], lo[1], lo[2], padoff, tile,
                       ty, z0, wy, xs0);

    // wave (64) reduction, then block sum
    float a = acc;
    #pragma unroll
    for (int o = 32; o > 0; o >>= 1)
        a += __shfl_down(a, o, 64);

    __shared__ float wsum[BLOCK_THREADS / 64];
    if ((tid & 63) == 0) wsum[tid >> 6] = a;
    __syncthreads();
    if (tid == 0) {
        float s = 0.f;
        #pragma unroll
        for (int w = 0; w < BLOCK_THREADS / 64; ++w) s += wsum[w];
        partials[blockIdx.x + (int)gridDim.x * (blockIdx.y + (int)gridDim.y * blockIdx.z)] = s;
    }
}

__global__ __launch_bounds__(256)
void ncc_reduce(const float* __restrict__ partials, int n, float* __restrict__ out)
{
    __shared__ double sh[256];
    double s = 0.0;
    for (int i = threadIdx.x; i < n; i += 256) s += (double)partials[i];
    sh[threadIdx.x] = s;
    __syncthreads();
    for (int off = 128; off > 0; off >>= 1) {
        if ((int)threadIdx.x < off) sh[threadIdx.x] += sh[threadIdx.x + off];
        __syncthreads();
    }
    if (threadIdx.x == 0) {
        const double nvox = (double)NB * NX * NY * NZ;
        out[0] = (float)(-sh[0] / nvox);
    }
}

extern "C" void kernel_launch(void* const* d_in, const int* in_sizes, int n_in,
                              void* d_out, int out_size, void* d_ws, size_t ws_size,
                              hipStream_t stream) {
    const float* pred  = (const float*)d_in[0];
    const float* label = (const float*)d_in[1];
    float* out = (float*)d_out;
    float* partials = (float*)d_ws;

    dim3 block(TZ, BY, 1);                 // 48 x 4 = 192 threads
    dim3 grid(NYB, NXB, NB);               // 48 x 24 x 2 = 2304 blocks

    ncc_partial<<<grid, block, 0, stream>>>(pred, label, partials);
    ncc_reduce<<<1, 256, 0, stream>>>(partials, NBLK, out);
}